// Round 7
// baseline (301.008 us; speedup 1.0000x reference)
//
#include <hip/hip_runtime.h>
#include <hip/hip_bf16.h>
#include <math.h>
#include <stdint.h>

// Problem: B=64, SQ=64, SD=512, H=128
#define BB 64
#define SQN 64
#define SDN 512
#define HH 128

typedef __attribute__((ext_vector_type(8))) short bf16x8;     // 8 bf16 = 4 VGPRs
typedef __attribute__((ext_vector_type(16))) float f32x16;    // 16 acc regs

__device__ __forceinline__ short f2bf(float f) {
  union { float f; unsigned u; } x; x.f = f;
  unsigned r = x.u + 0x7fffu + ((x.u >> 16) & 1u);   // RNE
  return (short)(r >> 16);
}

__device__ __forceinline__ void gl_lds16(const short* g, short* l) {
  __builtin_amdgcn_global_load_lds(
      (const __attribute__((address_space(1))) unsigned int*)g,
      (__attribute__((address_space(3))) unsigned int*)l, 16, 0, 0);
}

// ---- fused compact + fp32->bf16 convert (unchanged) -------------------------
__global__ __launch_bounds__(256)
void convert_all(const float* __restrict__ q, const float* __restrict__ dp,
                 const float* __restrict__ dn,
                 const int* __restrict__ mp, const int* __restrict__ mn,
                 short* __restrict__ oq, short* __restrict__ od,
                 int* __restrict__ nchunks, int* __restrict__ nvalid,
                 int* __restrict__ counter) {
  const int D_BLOCKS = (2 * BB * SDN) / 8;   // 8192 (8 rows/block, 32 thr/row)
  if (blockIdx.x < D_BLOCKS) {
    const int bs = blockIdx.x >> 6;          // 64 blocks per (side*64+b)
    const int j0 = (blockIdx.x & 63) * 8;    // first compacted row of block
    const int side = bs >> 6, b = bs & 63;
    const int* mask = (side ? mn : mp) + b * SDN;

    __shared__ int s_perm[8];
    __shared__ int s_pad32;

    if (threadIdx.x < 64) {                  // wave 0: exclusive scan of mask
      const int ln = threadIdx.x;
      int mreg[8];
      #pragma unroll
      for (int it = 0; it < 8; ++it) mreg[it] = mask[it * 64 + ln];
      int run = 0;
      #pragma unroll
      for (int it = 0; it < 8; ++it) {
        unsigned long long bal = __ballot(mreg[it] != 0);
        int pos = run + __popcll(bal & ((1ull << ln) - 1ull));
        if (mreg[it]) {
          unsigned rel = (unsigned)(pos - j0);
          if (rel < 8u) s_perm[rel] = it * 64 + ln;
        }
        run += (int)__popcll(bal);
      }
      if (ln < 8 && j0 + ln >= run) s_perm[ln] = -1;   // zero-fill slots
      if (ln == 0) {
        s_pad32 = (run + 31) & ~31;
        if (j0 == 0) {                       // one writer per bs
          nchunks[bs] = ((run + 127) & ~127) >> 7;
          nvalid[bs]  = run;
        }
      }
    }
    __syncthreads();

    const int j = j0 + (threadIdx.x >> 5);
    if (j >= s_pad32) return;                // never computed by maxsim
    const int l32 = threadIdx.x & 31;
    const int src_t = s_perm[threadIdx.x >> 5];
    const float* srcmat = side ? dn : dp;
    float4 v = make_float4(0.f, 0.f, 0.f, 0.f);
    if (src_t >= 0)
      v = ((const float4*)(srcmat + ((size_t)b * SDN + src_t) * HH))[l32];
    short4 o; o.x = f2bf(v.x); o.y = f2bf(v.y); o.z = f2bf(v.z); o.w = f2bf(v.w);
    *(short4*)&od[((size_t)bs * SDN + j) * HH + l32 * 4] = o;
  } else {
    if (blockIdx.x == D_BLOCKS && threadIdx.x == 0) *counter = 0;  // maxsim ticket
    int i = (blockIdx.x - D_BLOCKS) * 256 + threadIdx.x;  // float4 index, exact
    float4 v = ((const float4*)q)[i];
    short4 o; o.x = f2bf(v.x); o.y = f2bf(v.y); o.z = f2bf(v.z); o.w = f2bf(v.w);
    *(short4*)&oq[i * 4] = o;
  }
}

// Persistent maxsim — ROUND 7: ABLATION. Four structures (r3-r6) are
// invariant at 44-48us / ~30% MfmaUtil under wave-count x2, LDS traffic x4,
// chain count x2, sync-count x1.8, counted-vmcnt vs drain — every overlap
// theory nulled. Per-chunk wall 6.4k cyc vs MFMA 2.1k + LDS 1.9k + stage
// 0.4k: >=2k cyc unexplained. So this round ISOLATES the cost empirically:
//
//   V0 = exact r6 kernel (real scores + fused loss; the correctness path)
//   V1 = NO-MEMORY skeleton: no gl_lds/vmcnt in loop (slots 2,3 stale),
//        barriers + ds_read + MFMA + fmax kept; REP=3; writes scratch.
//   V3 = NO-BARRIER: full dataflow, vmcnt(4) self-pacing only, zero
//        s_barrier (racy LDS, timing-valid); REP=3; writes scratch.
//
// Decode: barrier cost = V0 - V3/3; memory cost = V0 - V1/3.
// V1/V3 touch only scratch; V0 path is byte-identical to r6 -> absmax 0.0.
template<int V>
__global__ __launch_bounds__(512, 4)
void maxsim_t(const short* __restrict__ qb,
              const short* __restrict__ dc,
              const int* __restrict__ nvalid,
              float* __restrict__ scores,
              int* __restrict__ counter,
              float* __restrict__ out,
              float* __restrict__ scratch) {
  const int lid  = blockIdx.x + 16 * blockIdx.y;   // 0..511
  const int xcd  = lid & 7;
  const int slot0= lid >> 3;                        // 0..63 within XCD
  const int aslc = slot0 & 15;
  const int bs0  = (xcd + 8 * (slot0 >> 4)) * 4;    // bgroup*4

  __shared__ __align__(16) short d_lds[4][64 * 128];  // 4 x 16 KB ring
  __shared__ float s_fin[4 * 64];                     // th1 -> th0 exchange
  __shared__ float s_out[16];                         // deferred scores
  __shared__ int s_ticket;
  __shared__ float part[16];

  const int tid = threadIdx.x;       // 0..511
  const int ln  = tid & 63;
  const int w   = tid >> 6;          // 0..7
  const int l31 = ln & 31;
  const int kh  = ln >> 5;
  const int aw  = w >> 1;            // 0..3: which query of this slice
  const int th  = w & 1;             // 32-row t-tile owned by this wave
  const int a   = aslc * 4 + aw;

  int nch[4], nvv[4];                // 64-row chunks per bs (block-uniform)
  #pragma unroll
  for (int i = 0; i < 4; ++i) {
    nvv[i] = nvalid[bs0 + i];
    nch[i] = (nvv[i] + 63) >> 6;
  }

  // ---- q as B-operand, BOTH s-halves: n = half*32+l31, k = kc*16+kh*8 ----
  bf16x8 qfrag[2][8];
  #pragma unroll
  for (int half = 0; half < 2; ++half) {
    const short* qrow = qb + ((size_t)a * SQN + half * 32 + l31) * HH + kh * 8;
    #pragma unroll
    for (int kc = 0; kc < 8; ++kc)
      qfrag[half][kc] = *(const bf16x8*)(qrow + kc * 16);
  }

  float rmaxh[2] = {0.f, 0.f};   // masked-zero trick: true max >= 0
  float vacc = 0.f;              // V1/V3 keep-alive accumulator

  // stage one full 64-row chunk (2 gl_lds16 per wave, constant count)
  auto STAGE = [&](int pbi, int ptc, int sl) {
    const short* dsrc = dc + ((size_t)(bs0 + pbi) * SDN + ptc * 64) * HH;
    short* dst = &d_lds[sl][0];
    #pragma unroll
    for (int it = 0; it < 2; ++it) {
      int f = it * 512 + tid;
      int row = f >> 4;                       // 0..63 within chunk
      int c = (f & 15) ^ (row & 15);
      gl_lds16(&dsrc[row * HH + c * 8], &dst[(it * 512 + w * 64) * 8]);
    }
  };

  const int NREP = (V == 0) ? 1 : 3;
  for (int rep = 0; rep < NREP; ++rep) {
    int pbi = 0, ptc = 0;
    if constexpr (V != 1) {
      // ---- prologue: P(0) -> slot0, P(1) -> slot1 ----
      STAGE(pbi, ptc, 0);
      if (++ptc == nch[pbi]) { ptc = 0; ++pbi; }
      STAGE(pbi, ptc, 1);
      if (++ptc == nch[pbi]) { ptc = 0; ++pbi; }
    } else {
      if (rep == 0) {                        // fill slots 0/1 once, drained
        STAGE(0, 0, 0);
        STAGE(0, (nch[0] > 1) ? 1 : 0, 1);
        asm volatile("s_waitcnt vmcnt(0)" ::: "memory");
        __syncthreads();
      }
    }

    int cbi = 0, ctc = 0, sl = 0;
    for (;;) {
      if constexpr (V != 1) {
        // ---- issue P(k+2); dummy re-stage of (0,0) at tail ----
        int qbi2 = (pbi < 4) ? pbi : 0;
        int qtc2 = (pbi < 4) ? ptc : 0;
        STAGE(qbi2, qtc2, (sl + 2) & 3);
        if (pbi < 4) { if (++ptc == nch[pbi]) { ptc = 0; ++pbi; } }
        // counted wait: own P(k) retired; P(k+1),P(k+2) stay in flight
        asm volatile("s_waitcnt vmcnt(4)" ::: "memory");
      }
      if constexpr (V != 3) __builtin_amdgcn_s_barrier();

      // ---- compute chunk (cbi,ctc): this wave's 32-row tile, both halves ----
      const int ntt = (ctc == nch[cbi] - 1)
                          ? ((nvv[cbi] - (ctc << 6) + 31) >> 5)   // 1..2, uniform
                          : 2;
      if (th < ntt) {
        const short* bufp = &d_lds[sl][0];
        int trow = th * 32 + l31;
        int tm = trow & 15;
        const short* bbase = &bufp[trow * HH];
        f32x16 acc0 = {0,0,0,0,0,0,0,0,0,0,0,0,0,0,0,0};
        f32x16 acc1 = {0,0,0,0,0,0,0,0,0,0,0,0,0,0,0,0};
        #pragma unroll
        for (int kc = 0; kc < 8; ++kc) {
          int c = (kc * 2 + kh) ^ tm;
          bf16x8 dfrag = *(const bf16x8*)&bbase[c * 8];  // A: m = t = trow
          acc0 = __builtin_amdgcn_mfma_f32_32x32x16_bf16(dfrag, qfrag[0][kc], acc0, 0, 0, 0);
          acc1 = __builtin_amdgcn_mfma_f32_32x32x16_bf16(dfrag, qfrag[1][kc], acc1, 0, 0, 0);
        }
        float m0 = acc0[0], m1 = acc1[0];
        #pragma unroll
        for (int r = 1; r < 16; ++r) {
          m0 = fmaxf(m0, acc0[r]);
          m1 = fmaxf(m1, acc1[r]);
        }
        rmaxh[0] = fmaxf(rmaxh[0], m0);
        rmaxh[1] = fmaxf(rmaxh[1], m1);
      }

      // ---- advance compute; finalize bs when it wraps (block-uniform) ----
      const int obi = cbi;
      const bool fin = (++ctc == nch[cbi]);
      if (fin) {
        ctc = 0; ++cbi;
        if constexpr (V == 0) {
          float v0 = fmaxf(rmaxh[0], __shfl_xor(rmaxh[0], 32));  // merge kh
          float v1 = fmaxf(rmaxh[1], __shfl_xor(rmaxh[1], 32));
          if (th && kh == 0) {                 // publish t-half-1 maxes
            s_fin[aw * 64 + l31]      = v0;
            s_fin[aw * 64 + 32 + l31] = v1;
          }
          __syncthreads();                     // 4x/block
          if (!th) {
            v0 = fmaxf(v0, s_fin[aw * 64 + l31]);        // exact max merge
            v1 = fmaxf(v1, s_fin[aw * 64 + 32 + l31]);
            float s = v0 + v1;                 // original operand order
            s += __shfl_xor(s, 1);  s += __shfl_xor(s, 2);  s += __shfl_xor(s, 4);
            s += __shfl_xor(s, 8);  s += __shfl_xor(s, 16);
            if (ln == 0) s_out[aw * 4 + obi] = s;   // defer global store
          }
        } else {
          vacc += rmaxh[0] + rmaxh[1];         // keep-alive, no sync
        }
        rmaxh[0] = 0.f; rmaxh[1] = 0.f;
      }

      if (cbi == 4) break;
      sl = (sl + 1) & 3;
    }
  }

  if constexpr (V != 0) {
    scratch[(size_t)lid * 512 + tid] = vacc;   // liveness; scratch-only
    return;
  }

  // ---- V0 epilogue: flush scores, fused loss via last-block ticket ----
  __syncthreads();                          // s_out visible; drains all VMEM
  if (w == 0 && ln < 16) {
    int ai = ln >> 2, bi = ln & 3;
    __hip_atomic_store(&scores[(size_t)(aslc * 4 + ai) * (2 * BB) + bs0 + bi],
                       s_out[ln], __ATOMIC_RELAXED, __HIP_MEMORY_SCOPE_AGENT);
  }
  asm volatile("s_waitcnt vmcnt(0)" ::: "memory");  // sc1 stores at LLC
  if (tid == 0)
    s_ticket = __hip_atomic_fetch_add(counter, 1,
                                      __ATOMIC_RELAXED, __HIP_MEMORY_SCOPE_AGENT);
  __syncthreads();
  if (s_ticket != 511) return;

  // Bitwise-identical replica of the original 16-partial loss reduction.
  if (w < 4) {
    #pragma unroll
    for (int q8 = 0; q8 < 4; ++q8) {
      int vp = w * 4 + q8;
      float acc = 0.f;
      #pragma unroll
      for (int i = 0; i < 4; ++i) {
        int r = vp * 4 + i;
        float v0 = __hip_atomic_load(&scores[r * 128 + ln],
                                     __ATOMIC_RELAXED, __HIP_MEMORY_SCOPE_AGENT);
        float v1 = __hip_atomic_load(&scores[r * 128 + 64 + ln],
                                     __ATOMIC_RELAXED, __HIP_MEMORY_SCOPE_AGENT);
        float mx = fmaxf(v0, v1);
        #pragma unroll
        for (int off = 32; off >= 1; off >>= 1) mx = fmaxf(mx, __shfl_xor(mx, off));
        float e = __expf(v0 - mx) + __expf(v1 - mx);
        #pragma unroll
        for (int off = 32; off >= 1; off >>= 1) e += __shfl_xor(e, off);
        float lse = mx + __logf(e);
        float diag = __shfl(v0, r);   // r < 64, diagonal lives in v0 at lane r
        acc += lse - diag;
      }
      if (ln == 0) part[vp] = acc;
    }
  }
  __syncthreads();
  if (w == 0) {
    float v = (ln < 16) ? part[ln] : 0.f;
    #pragma unroll
    for (int off = 8; off >= 1; off >>= 1) v += __shfl_xor(v, off);
    if (ln == 0) out[0] = v * (1.0f / 64.0f);
  }
}

extern "C" void kernel_launch(void* const* d_in, const int* in_sizes, int n_in,
                              void* d_out, int out_size, void* d_ws, size_t ws_size,
                              hipStream_t stream) {
  const float* q        = (const float*)d_in[0];
  const float* d_pos    = (const float*)d_in[1];
  const float* d_neg    = (const float*)d_in[2];
  const int*   mask_pos = (const int*)d_in[3];
  const int*   mask_neg = (const int*)d_in[4];

  // ws: q_bf 1MB | d_c 16MB | nchunks | nvalid | scores | counter | scratch 1MB
  short* q_bf = (short*)d_ws;                                  // 524288 shorts
  short* d_c  = q_bf + (size_t)BB * SQN * HH;                  // 8388608 shorts
  int*   nchunks = (int*)(d_c + (size_t)2 * BB * SDN * HH);    // 128 ints
  int*   nvalid  = nchunks + 128;                              // 128 ints
  float* scores  = (float*)(nvalid + 128);                     // 8192 floats
  int*   counter = (int*)(scores + 64 * 128);                  // 1 int
  float* scratch = (float*)(counter + 64);                     // 262144 floats

  const int D_BLOCKS = (2 * BB * SDN) / 8;          // 8192
  const int Q_BLOCKS = (BB * SQN * HH / 4) / 256;   // 512
  convert_all<<<D_BLOCKS + Q_BLOCKS, 256, 0, stream>>>(
      q, d_pos, d_neg, mask_pos, mask_neg, q_bf, d_c, nchunks, nvalid, counter);

  dim3 grid(16 /*a-slices*/, 32 /*b-groups*/);
  maxsim_t<0><<<grid, 512, 0, stream>>>(q_bf, d_c, nvalid, scores, counter,
                                        (float*)d_out, scratch);
  maxsim_t<1><<<grid, 512, 0, stream>>>(q_bf, d_c, nvalid, scores, counter,
                                        (float*)d_out, scratch);
  maxsim_t<3><<<grid, 512, 0, stream>>>(q_bf, d_c, nvalid, scores, counter,
                                        (float*)d_out, scratch);
}

// Round 8
// 136.321 us; speedup vs baseline: 2.2081x; 2.2081x over previous
//
#include <hip/hip_runtime.h>
#include <hip/hip_bf16.h>
#include <math.h>
#include <stdint.h>

// Problem: B=64, SQ=64, SD=512, H=128
#define BB 64
#define SQN 64
#define SDN 512
#define HH 128

typedef __attribute__((ext_vector_type(8))) short bf16x8;     // 8 bf16 = 4 VGPRs
typedef __attribute__((ext_vector_type(16))) float f32x16;    // 16 acc regs

__device__ __forceinline__ short f2bf(float f) {
  union { float f; unsigned u; } x; x.f = f;
  unsigned r = x.u + 0x7fffu + ((x.u >> 16) & 1u);   // RNE
  return (short)(r >> 16);
}

// ---- fused compact + fp32->bf16 convert, K-MAJOR d output -------------------
// d_ct layout: [bs][c][j][8] shorts, c = h/8 (16B h-chunk, 16 planes), j =
// compacted row. Maxsim's per-kc fragment load (lanes 0-31 = rows j..j+31 at
// fixed c) is then 512B-contiguous -> coalesced global_load_dwordx4, no LDS.
// Block = 16 j-rows x 16 c-planes (256 thr). Reads stay coalesced: lanes
// c=0..15 of one jrel read 512B of the source f32 row. Writes are 16B
// granules (scattered) - acceptable, convert is small.
// Rows written only up to pad32 = (valid+31)&~31; zero-filled for pad slots.
__global__ __launch_bounds__(256)
void convert_all(const float* __restrict__ q, const float* __restrict__ dp,
                 const float* __restrict__ dn,
                 const int* __restrict__ mp, const int* __restrict__ mn,
                 short* __restrict__ oq, short* __restrict__ od,
                 int* __restrict__ nvalid, int* __restrict__ counter) {
  const int D_BLOCKS = (2 * BB * SDN) / 16;   // 4096 (16 rows/block)
  if (blockIdx.x < D_BLOCKS) {
    const int bs = blockIdx.x >> 5;           // 32 blocks per (side*64+b)
    const int j0 = (blockIdx.x & 31) * 16;    // first compacted row of block
    const int side = bs >> 6, b = bs & 63;
    const int* mask = (side ? mn : mp) + b * SDN;

    __shared__ int s_perm[16];
    __shared__ int s_pad32;

    if (threadIdx.x < 64) {                   // wave 0: exclusive scan of mask
      const int ln = threadIdx.x;
      int mreg[8];
      #pragma unroll
      for (int it = 0; it < 8; ++it) mreg[it] = mask[it * 64 + ln];
      int run = 0;
      #pragma unroll
      for (int it = 0; it < 8; ++it) {
        unsigned long long bal = __ballot(mreg[it] != 0);
        int pos = run + __popcll(bal & ((1ull << ln) - 1ull));
        if (mreg[it]) {
          unsigned rel = (unsigned)(pos - j0);
          if (rel < 16u) s_perm[rel] = it * 64 + ln;
        }
        run += (int)__popcll(bal);
      }
      if (ln < 16 && j0 + ln >= run) s_perm[ln] = -1;   // zero-fill slots
      if (ln == 0) {
        s_pad32 = (run + 31) & ~31;
        if (j0 == 0) nvalid[bs] = run;        // one writer per bs
      }
    }
    __syncthreads();

    const int jrel = threadIdx.x >> 4;        // 0..15
    const int c    = threadIdx.x & 15;        // 0..15 h-chunk plane
    const int j    = j0 + jrel;
    if (j >= s_pad32) return;                 // never read by maxsim
    const int src_t = s_perm[jrel];
    const float* srcmat = side ? dn : dp;
    float4 va = make_float4(0.f, 0.f, 0.f, 0.f);
    float4 vb = make_float4(0.f, 0.f, 0.f, 0.f);
    if (src_t >= 0) {
      const float4* srow = (const float4*)(srcmat + ((size_t)b * SDN + src_t) * HH);
      va = srow[c * 2];
      vb = srow[c * 2 + 1];
    }
    bf16x8 o;
    o[0] = f2bf(va.x); o[1] = f2bf(va.y); o[2] = f2bf(va.z); o[3] = f2bf(va.w);
    o[4] = f2bf(vb.x); o[5] = f2bf(vb.y); o[6] = f2bf(vb.z); o[7] = f2bf(vb.w);
    *(bf16x8*)&od[(((size_t)bs * 16 + c) * 512 + j) * 8] = o;
  } else {
    if (blockIdx.x == D_BLOCKS && threadIdx.x == 0) *counter = 0;  // maxsim ticket
    int i = (blockIdx.x - D_BLOCKS) * 256 + threadIdx.x;  // float4 index, exact
    float4 v = ((const float4*)q)[i];
    short4 o; o.x = f2bf(v.x); o.y = f2bf(v.y); o.z = f2bf(v.z); o.w = f2bf(v.w);
    *(short4*)&oq[i * 4] = o;
  }
}

// Persistent maxsim — ROUND 8: BARRIER-FREE direct-global (ablation-driven).
//
// ROUND-7 ABLATION: V0(mem+bar)=48us, V1(bar only)=~29, V3(mem only)=~29.
// The 18us is the barrier x memory INTERACTION (per-chunk convoy); V3 proved
// full d-streaming with self-paced waves runs at ~29us. This kernel makes
// the barrier-free structure CORRECT by removing the reason for barriers:
// no cooperative LDS staging. Each wave loads its MFMA A-fragments directly
// global->VGPR from the k-major d_ct (per-kc: two 512B contiguous segments,
// coalesced). Main loop: ZERO barriers, ZERO LDS. d-reuse (2 aw-waves/block,
// 4 same-bgroup blocks/CU) is served by L1/L2.
//
// Block = 256 thr / 4 waves = (aw in 0..1) x (th in 0..1); block owns
// 2 queries (a = aslot*2+aw) x 4 bs. Grid 1024 = 32 aslots x 32 bgroups,
// __launch_bounds__(256,4) -> exactly 4 blocks/CU, 100% residency, no tail.
// Same-CU blocks have consecutive lids -> same bgroup -> shared d in L1/L2.
// XCD swizzle: each XCD owns 4 bgroups x 32 aslots (d-slice 2MB + q 1MB
// fits the 4MB per-XCD L2).
//
// Per-bs finalize: 2 __syncthreads (th-merge via s_fin + WAR protection);
// 8 barriers/kernel total, at bs granularity - negligible convoy cost.
// Trim: wave th computes chunk-tc tile iff th < ntt(tc) (rows < pad32 are
// always written by convert; beyond-pad rows never loaded).
// Bit-exactness: dfrag/qfrag bits, kc-chain order, fmax folds, kh-shfl,
// th-merge, s=v0+v1 + xor tree, loss replica all verbatim from r6 ->
// absmax 0.0. Handoff: sc1 relaxed agent atomics; each wave's stores drain
// at its own __syncthreads before the ticket; NO __threadfence (r2 lesson).
__global__ __launch_bounds__(256, 4)
void maxsim_kernel(const short* __restrict__ qb,
                   const short* __restrict__ dct,
                   const int* __restrict__ nvalid,
                   float* __restrict__ scores,
                   int* __restrict__ counter,
                   float* __restrict__ out) {
  const int lid   = blockIdx.x + 32 * blockIdx.y;  // 0..1023
  const int xcd   = lid & 7;
  const int slot  = lid >> 3;                       // 0..127 within XCD
  const int aslot = slot & 31;                      // 2 queries each
  const int bs0   = (xcd + 8 * (slot >> 5)) * 4;    // bgroup*4

  __shared__ float s_fin[2 * 2 * 32];   // [aw][half][l31] published by th=1
  __shared__ int s_ticket;
  __shared__ float part[16];

  const int tid = threadIdx.x;       // 0..255
  const int ln  = tid & 63;
  const int w   = tid >> 6;          // 0..3
  const int l31 = ln & 31;
  const int kh  = ln >> 5;
  const int aw  = w >> 1;            // which of the block's 2 queries
  const int th  = w & 1;             // 32-row t-tile owned within each chunk
  const int a   = aslot * 2 + aw;

  int nvv[4];
  #pragma unroll
  for (int i = 0; i < 4; ++i) nvv[i] = nvalid[bs0 + i];   // block-uniform

  // ---- q as B-operand, both s-halves: n = half*32+l31, k = kc*16+kh*8 ----
  bf16x8 qfrag[2][8];
  #pragma unroll
  for (int half = 0; half < 2; ++half) {
    const short* qrow = qb + ((size_t)a * SQN + half * 32 + l31) * HH + kh * 8;
    #pragma unroll
    for (int kc = 0; kc < 8; ++kc)
      qfrag[half][kc] = *(const bf16x8*)(qrow + kc * 16);
  }

  for (int bi = 0; bi < 4; ++bi) {
    const int nv   = nvv[bi];
    const int nc   = (nv + 63) >> 6;                  // 64-row chunks
    const int nttL = ((nv - ((nc - 1) << 6)) + 31) >> 5;  // 1..2 in last chunk
    const int myNT = (nc - 1) + (th < nttL ? 1 : 0);  // wave's tile count
    const short* base = dct + (size_t)(bs0 + bi) * 16 * 512 * 8;

    float rmaxh0 = 0.f, rmaxh1 = 0.f;    // masked-zero trick: true max >= 0

    for (int t = 0; t < myNT; ++t) {     // wave-uniform trip count
      const int row = t * 64 + th * 32 + l31;
      bf16x8 dv[8];
      #pragma unroll
      for (int kc = 0; kc < 8; ++kc)     // per kc: 2 x 512B coalesced segments
        dv[kc] = *(const bf16x8*)(base + (((kc * 2 + kh) * 512) + row) * 8);
      f32x16 acc0 = {0,0,0,0,0,0,0,0,0,0,0,0,0,0,0,0};
      f32x16 acc1 = {0,0,0,0,0,0,0,0,0,0,0,0,0,0,0,0};
      #pragma unroll
      for (int kc = 0; kc < 8; ++kc) {   // same chained order as r6
        acc0 = __builtin_amdgcn_mfma_f32_32x32x16_bf16(dv[kc], qfrag[0][kc], acc0, 0, 0, 0);
        acc1 = __builtin_amdgcn_mfma_f32_32x32x16_bf16(dv[kc], qfrag[1][kc], acc1, 0, 0, 0);
      }
      // C: col = l31 = s (within half), rows = 16 t's of this lane's kh group
      float m0 = acc0[0], m1 = acc1[0];
      #pragma unroll
      for (int r = 1; r < 16; ++r) {
        m0 = fmaxf(m0, acc0[r]);
        m1 = fmaxf(m1, acc1[r]);
      }
      rmaxh0 = fmaxf(rmaxh0, m0);
      rmaxh1 = fmaxf(rmaxh1, m1);
    }

    // ---- finalize bs(bi): cross-kh max, cross-th max, s-sum (r6 verbatim) ----
    float v0 = fmaxf(rmaxh0, __shfl_xor(rmaxh0, 32));  // merge kh t-halves
    float v1 = fmaxf(rmaxh1, __shfl_xor(rmaxh1, 32));
    if (th && kh == 0) {                 // publish t-half-1 maxes
      s_fin[(aw * 2 + 0) * 32 + l31] = v0;
      s_fin[(aw * 2 + 1) * 32 + l31] = v1;
    }
    __syncthreads();
    if (!th) {
      v0 = fmaxf(v0, s_fin[(aw * 2 + 0) * 32 + l31]);  // exact max merge
      v1 = fmaxf(v1, s_fin[(aw * 2 + 1) * 32 + l31]);
      float s = v0 + v1;                 // original operand order
      s += __shfl_xor(s, 1);  s += __shfl_xor(s, 2);  s += __shfl_xor(s, 4);
      s += __shfl_xor(s, 8);  s += __shfl_xor(s, 16);
      if (ln == 0)
        __hip_atomic_store(&scores[(size_t)a * (2 * BB) + bs0 + bi], s,
                           __ATOMIC_RELAXED, __HIP_MEMORY_SCOPE_AGENT);
    }
    __syncthreads();                     // WAR: s_fin reused next bi; also
  }                                      // drains each wave's own sc1 stores

  // ---- fused loss: last block to finish computes it (cache-op-free) ----
  if (tid == 0)
    s_ticket = __hip_atomic_fetch_add(counter, 1,
                                      __ATOMIC_RELAXED, __HIP_MEMORY_SCOPE_AGENT);
  __syncthreads();
  if (s_ticket != 1023) return;

  // Bitwise-identical replica of the original 16-partial loss reduction:
  // part[vp] (vp=0..15) covers rows 4vp..4vp+3; waves 0..3 compute vp=4w..4w+3;
  // wave 0 then runs the exact 16-lane xor tree. sc1 loads read the LLC.
  if (w < 4) {
    #pragma unroll
    for (int q8 = 0; q8 < 4; ++q8) {
      int vp = w * 4 + q8;
      float acc = 0.f;
      #pragma unroll
      for (int i = 0; i < 4; ++i) {
        int r = vp * 4 + i;
        float v0 = __hip_atomic_load(&scores[r * 128 + ln],
                                     __ATOMIC_RELAXED, __HIP_MEMORY_SCOPE_AGENT);
        float v1 = __hip_atomic_load(&scores[r * 128 + 64 + ln],
                                     __ATOMIC_RELAXED, __HIP_MEMORY_SCOPE_AGENT);
        float mx = fmaxf(v0, v1);
        #pragma unroll
        for (int off = 32; off >= 1; off >>= 1) mx = fmaxf(mx, __shfl_xor(mx, off));
        float e = __expf(v0 - mx) + __expf(v1 - mx);
        #pragma unroll
        for (int off = 32; off >= 1; off >>= 1) e += __shfl_xor(e, off);
        float lse = mx + __logf(e);
        float diag = __shfl(v0, r);   // r < 64, diagonal lives in v0 at lane r
        acc += lse - diag;
      }
      if (ln == 0) part[vp] = acc;
    }
  }
  __syncthreads();
  if (w == 0) {
    float v = (ln < 16) ? part[ln] : 0.f;
    #pragma unroll
    for (int off = 8; off >= 1; off >>= 1) v += __shfl_xor(v, off);
    if (ln == 0) out[0] = v * (1.0f / 64.0f);
  }
}

extern "C" void kernel_launch(void* const* d_in, const int* in_sizes, int n_in,
                              void* d_out, int out_size, void* d_ws, size_t ws_size,
                              hipStream_t stream) {
  const float* q        = (const float*)d_in[0];
  const float* d_pos    = (const float*)d_in[1];
  const float* d_neg    = (const float*)d_in[2];
  const int*   mask_pos = (const int*)d_in[3];
  const int*   mask_neg = (const int*)d_in[4];

  // ws layout: q_bf 1 MB | d_ct 16 MB (k-major) | nvalid | scores | counter
  short* q_bf = (short*)d_ws;                                  // 524288 shorts
  short* d_ct = q_bf + (size_t)BB * SQN * HH;                  // 8388608 shorts
  int*   nvalid  = (int*)(d_ct + (size_t)2 * BB * SDN * HH);   // 128 ints
  float* scores  = (float*)(nvalid + 128);                     // 8192 floats
  int*   counter = (int*)(scores + 64 * 128);                  // 1 int

  const int D_BLOCKS = (2 * BB * SDN) / 16;         // 4096
  const int Q_BLOCKS = (BB * SQN * HH / 4) / 256;   // 512
  convert_all<<<D_BLOCKS + Q_BLOCKS, 256, 0, stream>>>(
      q, d_pos, d_neg, mask_pos, mask_neg, q_bf, d_ct, nvalid, counter);

  dim3 grid(32 /*x: lid low bits*/, 32 /*y*/);
  maxsim_kernel<<<grid, 256, 0, stream>>>(q_bf, d_ct, nvalid, scores,
                                          counter, (float*)d_out);
}